// Round 11
// baseline (183.102 us; speedup 1.0000x reference)
//
#include <hip/hip_runtime.h>
#include <stdint.h>

#define B_ 4
#define N_ 16384
#define D_ 128
#define E_ 1048576
#define BN_ 65536          // B_*N_  (key = b*N+row fits in 16 bits)
#define NBKT 256           // buckets = key >> 8 ; 256 node-ids per bucket
#define NBLK 256           // scatter blocks; 4096 edges each
#define CAP  6144          // padded per-bucket arena capacity (mean 4096, sigma 64)
#define CAPH 3072          // half-bucket LDS sort arena (mean 2048, sigma 45)

typedef __attribute__((ext_vector_type(8))) short short8;
typedef __attribute__((ext_vector_type(4))) float floatx4;

// ---- workspace layout (bytes) ---- (no aliasing: pack1 read by k_spmm after matmul)
// ybf   : bf16-pairs u32 [BN_*64] @ 0         (16,777,216)
// pack1 : uint2 [NBKT*CAP] @ OFF_PACK1        (12,582,912)  bucket arena: x = nl<<14|col, y = val
// gbkt  : u32 [NBKT]       @ OFF_GBKT         (1,024 pad)   bucket fill counters
// norm  : f32 [BN_]        @ OFF_NORM         (262,144)
// WhG/WlG: u16[16384]      @ OFF_WH/WL        (32,768 each) fragment-layout split W
static constexpr size_t OFF_Y      = 0;
static constexpr size_t OFF_PACK1  = 16777216;
static constexpr size_t OFF_GBKT   = OFF_PACK1 + 12582912;
static constexpr size_t OFF_NORM   = OFF_GBKT + 1024;
static constexpr size_t OFF_WH     = OFF_NORM + 262144;
static constexpr size_t OFF_WL     = OFF_WH + 32768;

__device__ __forceinline__ uint32_t rne16(uint32_t u) {
    return (u + 0x7FFFu + ((u >> 16) & 1u)) >> 16;
}
__device__ __forceinline__ void bf16split(float f, uint16_t& h, uint16_t& l) {
    uint32_t hb = rne16(__float_as_uint(f));
    h = (uint16_t)hb;
    float r = f - __uint_as_float(hb << 16);
    l = (uint16_t)rne16(__float_as_uint(r));
}

// ---------------- phase 1: single-pass bucket scatter (register-held edges) ----------------
__global__ __launch_bounds__(1024, 2) void k_scatter(const int* __restrict__ eb,
                                                     const int* __restrict__ er,
                                                     const int* __restrict__ ec,
                                                     const float* __restrict__ ev,
                                                     const float* __restrict__ Wg,
                                                     uint32_t* __restrict__ gbkt,
                                                     uint2* __restrict__ pack1,
                                                     uint16_t* __restrict__ WhG,
                                                     uint16_t* __restrict__ WlG) {
    __shared__ uint32_t h[NBKT];       // counts -> run cursors
    int t = threadIdx.x;
    if (t < NBKT) h[t] = 0;
    // fused W split/transpose into MFMA B-fragment chunk layout (blocks 0..15)
    if (blockIdx.x < 16) {
        int g = blockIdx.x * 1024 + t;
        float w = Wg[g];
        uint16_t hh, ll;
        bf16split(w, hh, ll);
        int k = g >> 7, n = g & 127;
        int o = ((k >> 3) * 128 + n) * 8 + (k & 7);
        WhG[o] = hh;
        WlG[o] = ll;
    }
    __syncthreads();
    int vbase = blockIdx.x * 1024 + t;        // int4 index: 4 edges per thread
    int4   b4 = ((const int4*)eb)[vbase];
    int4   r4 = ((const int4*)er)[vbase];
    int4   c4 = ((const int4*)ec)[vbase];
    float4 v4 = ((const float4*)ev)[vbase];
    uint32_t k0 = (uint32_t)(b4.x * N_ + r4.x);
    uint32_t k1 = (uint32_t)(b4.y * N_ + r4.y);
    uint32_t k2 = (uint32_t)(b4.z * N_ + r4.z);
    uint32_t k3 = (uint32_t)(b4.w * N_ + r4.w);
    atomicAdd(&h[k0 >> 8], 1u);
    atomicAdd(&h[k1 >> 8], 1u);
    atomicAdd(&h[k2 >> 8], 1u);
    atomicAdd(&h[k3 >> 8], 1u);
    __syncthreads();
    if (t < NBKT) {
        uint32_t c = h[t];
        uint32_t base = c ? atomicAdd(&gbkt[t], c) : 0u;
        h[t] = base;                   // becomes run cursor
    }
    __syncthreads();
    {
        uint32_t off = atomicAdd(&h[k0 >> 8], 1u);
        pack1[(size_t)(k0 >> 8) * CAP + off] =
            make_uint2(((k0 & 255u) << 14) | (uint32_t)c4.x, __float_as_uint(v4.x));
    }
    {
        uint32_t off = atomicAdd(&h[k1 >> 8], 1u);
        pack1[(size_t)(k1 >> 8) * CAP + off] =
            make_uint2(((k1 & 255u) << 14) | (uint32_t)c4.y, __float_as_uint(v4.y));
    }
    {
        uint32_t off = atomicAdd(&h[k2 >> 8], 1u);
        pack1[(size_t)(k2 >> 8) * CAP + off] =
            make_uint2(((k2 & 255u) << 14) | (uint32_t)c4.z, __float_as_uint(v4.z));
    }
    {
        uint32_t off = atomicAdd(&h[k3 >> 8], 1u);
        pack1[(size_t)(k3 >> 8) * CAP + off] =
            make_uint2(((k3 & 255u) << 14) | (uint32_t)c4.w, __float_as_uint(v4.w));
    }
}

// ---------------- phase 2: per-bucket degree -> norm (one block per bucket) ----------------
__global__ __launch_bounds__(1024) void k_deg(const uint32_t* __restrict__ gbkt,
                                              const uint2* __restrict__ pack1,
                                              float* __restrict__ norm) {
    __shared__ float dsum[NBKT];
    int t = threadIdx.x;
    int bkt = blockIdx.x;
    if (t < NBKT) dsum[t] = 0.f;
    __syncthreads();
    uint32_t cnt = gbkt[bkt];
    size_t bstart = (size_t)bkt * CAP;
    for (uint32_t i = t; i < cnt; i += 1024) {
        uint2 p = pack1[bstart + i];
        atomicAdd(&dsum[p.x >> 14], fabsf(__uint_as_float(p.y)));
    }
    __syncthreads();
    if (t < NBKT) norm[bkt * NBKT + t] = rsqrtf(dsum[t] + 1e-6f);
}

// ---------------- y = (x @ W) * norm via split-bf16 MFMA, stored packed bf16 ----------------
__global__ __launch_bounds__(256) void k_matmul_mfma(const float* __restrict__ x,
                                                     const uint16_t* __restrict__ WhG,
                                                     const uint16_t* __restrict__ WlG,
                                                     const float* __restrict__ norm,
                                                     uint32_t* __restrict__ ybf) {
    __shared__ short WhS[16384];   // 32 KB
    __shared__ short WlS[16384];   // 32 KB
    __shared__ short XhS[4096];    //  8 KB
    __shared__ short XlS[4096];    //  8 KB
    __shared__ float normS[32];
    int tid = threadIdx.x;
    int row0 = blockIdx.x * 32;

    {
        const uint4* whg = (const uint4*)WhG;
        const uint4* wlg = (const uint4*)WlG;
        uint4* whs = (uint4*)WhS;
        uint4* wls = (uint4*)WlS;
#pragma unroll
        for (int i = 0; i < 8; ++i) {
            whs[i * 256 + tid] = whg[i * 256 + tid];
            wls[i * 256 + tid] = wlg[i * 256 + tid];
        }
    }
#pragma unroll
    for (int cc = 0; cc < 2; ++cc) {
        int c = cc * 256 + tid;            // chunk id
        int m = c & 31, kk = c >> 5;
        const float4* xp = (const float4*)(x + (size_t)(row0 + m) * D_ + kk * 8);
        float4 f0 = xp[0], f1 = xp[1];
        union { short8 v; uint16_t s[8]; } uh, ul;
        bf16split(f0.x, uh.s[0], ul.s[0]); bf16split(f0.y, uh.s[1], ul.s[1]);
        bf16split(f0.z, uh.s[2], ul.s[2]); bf16split(f0.w, uh.s[3], ul.s[3]);
        bf16split(f1.x, uh.s[4], ul.s[4]); bf16split(f1.y, uh.s[5], ul.s[5]);
        bf16split(f1.z, uh.s[6], ul.s[6]); bf16split(f1.w, uh.s[7], ul.s[7]);
        ((short8*)XhS)[c] = uh.v;
        ((short8*)XlS)[c] = ul.v;
    }
    if (tid < 32) normS[tid] = norm[row0 + tid];
    __syncthreads();

    int lane = tid & 63;
    int wv = tid >> 6;
    int quad = lane >> 4;
    int l15 = lane & 15;
    int wcol0 = wv * 32;
    floatx4 acc[2][2] = {};
    const short8* Xh8 = (const short8*)XhS;
    const short8* Xl8 = (const short8*)XlS;
    const short8* Wh8 = (const short8*)WhS;
    const short8* Wl8 = (const short8*)WlS;
#pragma unroll
    for (int ks = 0; ks < 4; ++ks) {
        int kkq = ks * 4 + quad;
        short8 ah0 = Xh8[kkq * 32 + l15];
        short8 ah1 = Xh8[kkq * 32 + 16 + l15];
        short8 al0 = Xl8[kkq * 32 + l15];
        short8 al1 = Xl8[kkq * 32 + 16 + l15];
        short8 bh0 = Wh8[kkq * 128 + wcol0 + l15];
        short8 bh1 = Wh8[kkq * 128 + wcol0 + 16 + l15];
        short8 bl0 = Wl8[kkq * 128 + wcol0 + l15];
        short8 bl1 = Wl8[kkq * 128 + wcol0 + 16 + l15];
        acc[0][0] = __builtin_amdgcn_mfma_f32_16x16x32_bf16(ah0, bh0, acc[0][0], 0, 0, 0);
        acc[0][1] = __builtin_amdgcn_mfma_f32_16x16x32_bf16(ah0, bh1, acc[0][1], 0, 0, 0);
        acc[1][0] = __builtin_amdgcn_mfma_f32_16x16x32_bf16(ah1, bh0, acc[1][0], 0, 0, 0);
        acc[1][1] = __builtin_amdgcn_mfma_f32_16x16x32_bf16(ah1, bh1, acc[1][1], 0, 0, 0);
        acc[0][0] = __builtin_amdgcn_mfma_f32_16x16x32_bf16(ah0, bl0, acc[0][0], 0, 0, 0);
        acc[0][1] = __builtin_amdgcn_mfma_f32_16x16x32_bf16(ah0, bl1, acc[0][1], 0, 0, 0);
        acc[1][0] = __builtin_amdgcn_mfma_f32_16x16x32_bf16(ah1, bl0, acc[1][0], 0, 0, 0);
        acc[1][1] = __builtin_amdgcn_mfma_f32_16x16x32_bf16(ah1, bl1, acc[1][1], 0, 0, 0);
        acc[0][0] = __builtin_amdgcn_mfma_f32_16x16x32_bf16(al0, bh0, acc[0][0], 0, 0, 0);
        acc[0][1] = __builtin_amdgcn_mfma_f32_16x16x32_bf16(al0, bh1, acc[0][1], 0, 0, 0);
        acc[1][0] = __builtin_amdgcn_mfma_f32_16x16x32_bf16(al1, bh0, acc[1][0], 0, 0, 0);
        acc[1][1] = __builtin_amdgcn_mfma_f32_16x16x32_bf16(al1, bh1, acc[1][1], 0, 0, 0);
    }

#pragma unroll
    for (int rt = 0; rt < 2; ++rt) {
#pragma unroll
        for (int ct = 0; ct < 2; ++ct) {
            floatx4 v = acc[rt][ct];
            int rbase = rt * 16 + quad * 4;
            int cp = (wcol0 + ct * 16) / 2 + (l15 >> 1);
#pragma unroll
            for (int r = 0; r < 4; ++r) {
                float mine = v[r] * normS[rbase + r];
                float oth = __shfl_xor(mine, 1, 64);
                uint32_t a = __float_as_uint((lane & 1) ? oth : mine);   // even col
                uint32_t b = __float_as_uint((lane & 1) ? mine : oth);   // odd col
                uint32_t packed = rne16(a) | (rne16(b) << 16);
                bool doit = ((lane & 1) == 0) ? (r < 2) : (r >= 2);
                if (doit)
                    ybf[(size_t)(row0 + rbase + r) * 64 + cp] = packed;
            }
        }
    }
}

// ---------------- SpMM: 512 blocks = (bucket, half); LDS counting sort + register gather ------
// grid split fixes R10's 1-block/CU cap: LDS ~26 KB, 2 blocks/CU -> 32 waves/CU.
__device__ __forceinline__ void fma8(float* acc, float v, uint4 u) {
    acc[0] = fmaf(v, __uint_as_float(u.x << 16), acc[0]);
    acc[1] = fmaf(v, __uint_as_float(u.x & 0xFFFF0000u), acc[1]);
    acc[2] = fmaf(v, __uint_as_float(u.y << 16), acc[2]);
    acc[3] = fmaf(v, __uint_as_float(u.y & 0xFFFF0000u), acc[3]);
    acc[4] = fmaf(v, __uint_as_float(u.z << 16), acc[4]);
    acc[5] = fmaf(v, __uint_as_float(u.z & 0xFFFF0000u), acc[5]);
    acc[6] = fmaf(v, __uint_as_float(u.w << 16), acc[6]);
    acc[7] = fmaf(v, __uint_as_float(u.w & 0xFFFF0000u), acc[7]);
}

__global__ __launch_bounds__(1024, 2) void k_spmm(const uint32_t* __restrict__ gbkt,
                                                  const uint2* __restrict__ pack1,
                                                  const uint4* __restrict__ y4,
                                                  const float* __restrict__ norm,
                                                  const float* __restrict__ bias,
                                                  float* __restrict__ out) {
    __shared__ uint2    srt[CAPH];     // 24 KB (node-sorted half-bucket)
    __shared__ uint32_t cnt[128];
    __shared__ uint32_t scn[128];      // inclusive scan = row END
    __shared__ uint32_t rcur[128];
    int t = threadIdx.x;
    // blk = 8*j + 4*half + batch : XCD = blk%8 pinned to one batch's 4MB y-slab
    int blk = blockIdx.x;              // 0..511
    int xcd = blk & 7;
    int batch = xcd & 3;
    int half = xcd >> 2;
    int j = blk >> 3;                  // 0..63
    int bkt = batch * 64 + j;
    if (t < 128) cnt[t] = 0;
    __syncthreads();
    uint32_t n = gbkt[bkt];
    size_t base = (size_t)bkt * CAP;
    for (uint32_t i = t; i < n; i += 1024) {
        uint2 p = pack1[base + i];
        uint32_t nl = p.x >> 14;
        if ((int)(nl >> 7) == half) atomicAdd(&cnt[nl & 127], 1u);
    }
    __syncthreads();
    if (t < 128) scn[t] = cnt[t];
    __syncthreads();
    for (int off = 1; off < 128; off <<= 1) {
        uint32_t a = 0;
        if (t < 128 && t >= off) a = scn[t - off];
        __syncthreads();
        if (t < 128) scn[t] += a;
        __syncthreads();
    }
    if (t < 128) rcur[t] = scn[t] - cnt[t];
    __syncthreads();
    for (uint32_t i = t; i < n; i += 1024) {
        uint2 p = pack1[base + i];         // L2-warm re-read
        uint32_t nl = p.x >> 14;
        if ((int)(nl >> 7) == half) {
            uint32_t pos = atomicAdd(&rcur[nl & 127], 1u);
            srt[pos] = p;
        }
    }
    __syncthreads();

    int wv = t >> 6;                   // 16 waves x 8 nodes each
    int lane = t & 63;
    int esub = lane >> 4;
    int chunk = lane & 15;
    uint32_t colbase = (uint32_t)batch << 14;   // batch*N_
#pragma unroll 1
    for (int i = 0; i < 8; ++i) {
        int nl = wv * 8 + i;           // 0..127 local
        uint32_t end = scn[nl];
        uint32_t e = end - cnt[nl];
        float acc[8] = {0.f,0.f,0.f,0.f,0.f,0.f,0.f,0.f};
        for (; e + 16 <= end; e += 16) {
            uint2 pa = srt[e + esub];
            uint2 pb = srt[e + 4 + esub];
            uint2 pc = srt[e + 8 + esub];
            uint2 pd = srt[e + 12 + esub];
            uint4 ua = y4[(size_t)(colbase | (pa.x & 0x3FFFu)) * 16 + chunk];
            uint4 ub = y4[(size_t)(colbase | (pb.x & 0x3FFFu)) * 16 + chunk];
            uint4 uc = y4[(size_t)(colbase | (pc.x & 0x3FFFu)) * 16 + chunk];
            uint4 ud = y4[(size_t)(colbase | (pd.x & 0x3FFFu)) * 16 + chunk];
            fma8(acc, __uint_as_float(pa.y), ua);
            fma8(acc, __uint_as_float(pb.y), ub);
            fma8(acc, __uint_as_float(pc.y), uc);
            fma8(acc, __uint_as_float(pd.y), ud);
        }
        for (; e + 4 <= end; e += 4) {
            uint2 p = srt[e + esub];
            uint4 u = y4[(size_t)(colbase | (p.x & 0x3FFFu)) * 16 + chunk];
            fma8(acc, __uint_as_float(p.y), u);
        }
        if (e < end) {
            uint32_t idx = e + esub;
            bool act = idx < end;
            uint2 p = srt[act ? idx : (end - 1)];
            uint4 u = y4[(size_t)(colbase | (p.x & 0x3FFFu)) * 16 + chunk];
            float v = act ? __uint_as_float(p.y) : 0.f;
            fma8(acc, v, u);
        }
#pragma unroll
        for (int jj = 0; jj < 8; ++jj) {
            acc[jj] += __shfl_xor(acc[jj], 16, 64);
            acc[jj] += __shfl_xor(acc[jj], 32, 64);
        }
        if (esub < 2) {
            int node = bkt * NBKT + half * 128 + nl;
            float nm = norm[node];
            float4 bb = ((const float4*)bias)[chunk * 2 + esub];
            float4 o;
            o.x = fmaxf(fmaf(acc[esub * 4 + 0], nm, bb.x), 0.f);
            o.y = fmaxf(fmaf(acc[esub * 4 + 1], nm, bb.y), 0.f);
            o.z = fmaxf(fmaf(acc[esub * 4 + 2], nm, bb.z), 0.f);
            o.w = fmaxf(fmaf(acc[esub * 4 + 3], nm, bb.w), 0.f);
            ((float4*)out)[(size_t)node * 32 + chunk * 2 + esub] = o;
        }
    }
}

extern "C" void kernel_launch(void* const* d_in, const int* in_sizes, int n_in,
                              void* d_out, int out_size, void* d_ws, size_t ws_size,
                              hipStream_t stream) {
    const float* x  = (const float*)d_in[0];
    const float* W  = (const float*)d_in[1];
    const float* bi = (const float*)d_in[2];
    const int* eb   = (const int*)d_in[3];
    const int* er   = (const int*)d_in[4];
    const int* ec   = (const int*)d_in[5];
    const float* ev = (const float*)d_in[6];
    float* out = (float*)d_out;

    char* ws = (char*)d_ws;
    uint32_t* ybf    = (uint32_t*)(ws + OFF_Y);
    uint2*    pack1  = (uint2*)(ws + OFF_PACK1);
    uint32_t* gbkt   = (uint32_t*)(ws + OFF_GBKT);
    float*    norm   = (float*)(ws + OFF_NORM);
    uint16_t* WhG    = (uint16_t*)(ws + OFF_WH);
    uint16_t* WlG    = (uint16_t*)(ws + OFF_WL);

    hipMemsetAsync(gbkt, 0, NBKT * sizeof(uint32_t), stream);
    k_scatter<<<NBLK, 1024, 0, stream>>>(eb, er, ec, ev, W, gbkt, pack1, WhG, WlG);
    k_deg    <<<NBKT, 1024, 0, stream>>>(gbkt, pack1, norm);
    k_matmul_mfma<<<BN_ / 32, 256, 0, stream>>>(x, WhG, WlG, norm, ybf);
    k_spmm   <<<512, 1024, 0, stream>>>(gbkt, pack1, (const uint4*)ybf, norm, bi, out);
}

// Round 12
// 179.610 us; speedup vs baseline: 1.0194x; 1.0194x over previous
//
#include <hip/hip_runtime.h>
#include <stdint.h>

#define B_ 4
#define N_ 16384
#define D_ 128
#define E_ 1048576
#define BN_ 65536          // B_*N_  (key = b*N+row fits in 16 bits)
#define NBKT 256           // buckets = key >> 8 ; 256 node-ids per bucket
#define NBLK 256           // scatter blocks; 4096 edges each
#define CAP  6144          // padded per-bucket arena capacity (mean 4096, sigma 64)
#define CAPQ 1536          // quarter-bucket LDS sort arena (mean 1024, sigma 32)

typedef __attribute__((ext_vector_type(8))) short short8;
typedef __attribute__((ext_vector_type(4))) float floatx4;

// ---- workspace layout (bytes) ---- (no aliasing: pack1 read by k_spmm after matmul)
// ybf    : bf16-pairs u32 [BN_*64] @ 0         (16,777,216)
// pack1  : uint2 [NBKT*CAP] @ OFF_PACK1        (12,582,912)  bucket arena: x = nl<<14|col, y = val
// gbkt   : u32 [NBKT]       @ OFF_GBKT         (1,024 pad)   bucket fill counters
// norm   : f32 [BN_]        @ OFF_NORM         (262,144)
// rowst  : u32 [BN_]        @ OFF_ROWST        (262,144)     bucket-local exclusive row starts
// WhG/WlG: u16[16384]       @ OFF_WH/WL        (32,768 each) fragment-layout split W
static constexpr size_t OFF_Y      = 0;
static constexpr size_t OFF_PACK1  = 16777216;
static constexpr size_t OFF_GBKT   = OFF_PACK1 + 12582912;
static constexpr size_t OFF_NORM   = OFF_GBKT + 1024;
static constexpr size_t OFF_ROWST  = OFF_NORM + 262144;
static constexpr size_t OFF_WH     = OFF_ROWST + 262144;
static constexpr size_t OFF_WL     = OFF_WH + 32768;

__device__ __forceinline__ uint32_t rne16(uint32_t u) {
    return (u + 0x7FFFu + ((u >> 16) & 1u)) >> 16;
}
__device__ __forceinline__ void bf16split(float f, uint16_t& h, uint16_t& l) {
    uint32_t hb = rne16(__float_as_uint(f));
    h = (uint16_t)hb;
    float r = f - __uint_as_float(hb << 16);
    l = (uint16_t)rne16(__float_as_uint(r));
}

// ---------------- phase 1: single-pass bucket scatter (register-held edges) ----------------
__global__ __launch_bounds__(1024, 2) void k_scatter(const int* __restrict__ eb,
                                                     const int* __restrict__ er,
                                                     const int* __restrict__ ec,
                                                     const float* __restrict__ ev,
                                                     const float* __restrict__ Wg,
                                                     uint32_t* __restrict__ gbkt,
                                                     uint2* __restrict__ pack1,
                                                     uint16_t* __restrict__ WhG,
                                                     uint16_t* __restrict__ WlG) {
    __shared__ uint32_t h[NBKT];       // counts -> run cursors
    int t = threadIdx.x;
    if (t < NBKT) h[t] = 0;
    // fused W split/transpose into MFMA B-fragment chunk layout (blocks 0..15)
    if (blockIdx.x < 16) {
        int g = blockIdx.x * 1024 + t;
        float w = Wg[g];
        uint16_t hh, ll;
        bf16split(w, hh, ll);
        int k = g >> 7, n = g & 127;
        int o = ((k >> 3) * 128 + n) * 8 + (k & 7);
        WhG[o] = hh;
        WlG[o] = ll;
    }
    __syncthreads();
    int vbase = blockIdx.x * 1024 + t;        // int4 index: 4 edges per thread
    int4   b4 = ((const int4*)eb)[vbase];
    int4   r4 = ((const int4*)er)[vbase];
    int4   c4 = ((const int4*)ec)[vbase];
    float4 v4 = ((const float4*)ev)[vbase];
    uint32_t k0 = (uint32_t)(b4.x * N_ + r4.x);
    uint32_t k1 = (uint32_t)(b4.y * N_ + r4.y);
    uint32_t k2 = (uint32_t)(b4.z * N_ + r4.z);
    uint32_t k3 = (uint32_t)(b4.w * N_ + r4.w);
    atomicAdd(&h[k0 >> 8], 1u);
    atomicAdd(&h[k1 >> 8], 1u);
    atomicAdd(&h[k2 >> 8], 1u);
    atomicAdd(&h[k3 >> 8], 1u);
    __syncthreads();
    if (t < NBKT) {
        uint32_t c = h[t];
        uint32_t base = c ? atomicAdd(&gbkt[t], c) : 0u;
        h[t] = base;                   // becomes run cursor
    }
    __syncthreads();
    {
        uint32_t off = atomicAdd(&h[k0 >> 8], 1u);
        pack1[(size_t)(k0 >> 8) * CAP + off] =
            make_uint2(((k0 & 255u) << 14) | (uint32_t)c4.x, __float_as_uint(v4.x));
    }
    {
        uint32_t off = atomicAdd(&h[k1 >> 8], 1u);
        pack1[(size_t)(k1 >> 8) * CAP + off] =
            make_uint2(((k1 & 255u) << 14) | (uint32_t)c4.y, __float_as_uint(v4.y));
    }
    {
        uint32_t off = atomicAdd(&h[k2 >> 8], 1u);
        pack1[(size_t)(k2 >> 8) * CAP + off] =
            make_uint2(((k2 & 255u) << 14) | (uint32_t)c4.z, __float_as_uint(v4.z));
    }
    {
        uint32_t off = atomicAdd(&h[k3 >> 8], 1u);
        pack1[(size_t)(k3 >> 8) * CAP + off] =
            make_uint2(((k3 & 255u) << 14) | (uint32_t)c4.w, __float_as_uint(v4.w));
    }
}

// ---------------- phase 2: per-bucket degree -> norm AND row starts (one block per bucket) -----
__global__ __launch_bounds__(1024) void k_degsort(const uint32_t* __restrict__ gbkt,
                                                  const uint2* __restrict__ pack1,
                                                  float* __restrict__ norm,
                                                  uint32_t* __restrict__ rowst) {
    __shared__ float    dsum[NBKT];
    __shared__ uint32_t cnt[NBKT];
    __shared__ uint32_t scn[NBKT];
    int t = threadIdx.x;
    int bkt = blockIdx.x;
    if (t < NBKT) { dsum[t] = 0.f; cnt[t] = 0; }
    __syncthreads();
    uint32_t n = gbkt[bkt];
    size_t bstart = (size_t)bkt * CAP;
    for (uint32_t i = t; i < n; i += 1024) {
        uint2 p = pack1[bstart + i];
        uint32_t nl = p.x >> 14;
        atomicAdd(&cnt[nl], 1u);
        atomicAdd(&dsum[nl], fabsf(__uint_as_float(p.y)));
    }
    __syncthreads();
    if (t < NBKT) scn[t] = cnt[t];
    __syncthreads();
    for (int off = 1; off < NBKT; off <<= 1) {
        uint32_t a = 0;
        if (t < NBKT && t >= off) a = scn[t - off];
        __syncthreads();
        if (t < NBKT) scn[t] += a;
        __syncthreads();
    }
    if (t < NBKT) {
        norm[bkt * NBKT + t] = rsqrtf(dsum[t] + 1e-6f);
        rowst[bkt * NBKT + t] = scn[t] - cnt[t];    // bucket-local exclusive start
    }
}

// ---------------- y = (x @ W) * norm via split-bf16 MFMA, stored packed bf16 ----------------
__global__ __launch_bounds__(256) void k_matmul_mfma(const float* __restrict__ x,
                                                     const uint16_t* __restrict__ WhG,
                                                     const uint16_t* __restrict__ WlG,
                                                     const float* __restrict__ norm,
                                                     uint32_t* __restrict__ ybf) {
    __shared__ short WhS[16384];   // 32 KB
    __shared__ short WlS[16384];   // 32 KB
    __shared__ short XhS[4096];    //  8 KB
    __shared__ short XlS[4096];    //  8 KB
    __shared__ float normS[32];
    int tid = threadIdx.x;
    int row0 = blockIdx.x * 32;

    {
        const uint4* whg = (const uint4*)WhG;
        const uint4* wlg = (const uint4*)WlG;
        uint4* whs = (uint4*)WhS;
        uint4* wls = (uint4*)WlS;
#pragma unroll
        for (int i = 0; i < 8; ++i) {
            whs[i * 256 + tid] = whg[i * 256 + tid];
            wls[i * 256 + tid] = wlg[i * 256 + tid];
        }
    }
#pragma unroll
    for (int cc = 0; cc < 2; ++cc) {
        int c = cc * 256 + tid;            // chunk id
        int m = c & 31, kk = c >> 5;
        const float4* xp = (const float4*)(x + (size_t)(row0 + m) * D_ + kk * 8);
        float4 f0 = xp[0], f1 = xp[1];
        union { short8 v; uint16_t s[8]; } uh, ul;
        bf16split(f0.x, uh.s[0], ul.s[0]); bf16split(f0.y, uh.s[1], ul.s[1]);
        bf16split(f0.z, uh.s[2], ul.s[2]); bf16split(f0.w, uh.s[3], ul.s[3]);
        bf16split(f1.x, uh.s[4], ul.s[4]); bf16split(f1.y, uh.s[5], ul.s[5]);
        bf16split(f1.z, uh.s[6], ul.s[6]); bf16split(f1.w, uh.s[7], ul.s[7]);
        ((short8*)XhS)[c] = uh.v;
        ((short8*)XlS)[c] = ul.v;
    }
    if (tid < 32) normS[tid] = norm[row0 + tid];
    __syncthreads();

    int lane = tid & 63;
    int wv = tid >> 6;
    int quad = lane >> 4;
    int l15 = lane & 15;
    int wcol0 = wv * 32;
    floatx4 acc[2][2] = {};
    const short8* Xh8 = (const short8*)XhS;
    const short8* Xl8 = (const short8*)XlS;
    const short8* Wh8 = (const short8*)WhS;
    const short8* Wl8 = (const short8*)WlS;
#pragma unroll
    for (int ks = 0; ks < 4; ++ks) {
        int kkq = ks * 4 + quad;
        short8 ah0 = Xh8[kkq * 32 + l15];
        short8 ah1 = Xh8[kkq * 32 + 16 + l15];
        short8 al0 = Xl8[kkq * 32 + l15];
        short8 al1 = Xl8[kkq * 32 + 16 + l15];
        short8 bh0 = Wh8[kkq * 128 + wcol0 + l15];
        short8 bh1 = Wh8[kkq * 128 + wcol0 + 16 + l15];
        short8 bl0 = Wl8[kkq * 128 + wcol0 + l15];
        short8 bl1 = Wl8[kkq * 128 + wcol0 + 16 + l15];
        acc[0][0] = __builtin_amdgcn_mfma_f32_16x16x32_bf16(ah0, bh0, acc[0][0], 0, 0, 0);
        acc[0][1] = __builtin_amdgcn_mfma_f32_16x16x32_bf16(ah0, bh1, acc[0][1], 0, 0, 0);
        acc[1][0] = __builtin_amdgcn_mfma_f32_16x16x32_bf16(ah1, bh0, acc[1][0], 0, 0, 0);
        acc[1][1] = __builtin_amdgcn_mfma_f32_16x16x32_bf16(ah1, bh1, acc[1][1], 0, 0, 0);
        acc[0][0] = __builtin_amdgcn_mfma_f32_16x16x32_bf16(ah0, bl0, acc[0][0], 0, 0, 0);
        acc[0][1] = __builtin_amdgcn_mfma_f32_16x16x32_bf16(ah0, bl1, acc[0][1], 0, 0, 0);
        acc[1][0] = __builtin_amdgcn_mfma_f32_16x16x32_bf16(ah1, bl0, acc[1][0], 0, 0, 0);
        acc[1][1] = __builtin_amdgcn_mfma_f32_16x16x32_bf16(ah1, bl1, acc[1][1], 0, 0, 0);
        acc[0][0] = __builtin_amdgcn_mfma_f32_16x16x32_bf16(al0, bh0, acc[0][0], 0, 0, 0);
        acc[0][1] = __builtin_amdgcn_mfma_f32_16x16x32_bf16(al0, bh1, acc[0][1], 0, 0, 0);
        acc[1][0] = __builtin_amdgcn_mfma_f32_16x16x32_bf16(al1, bh0, acc[1][0], 0, 0, 0);
        acc[1][1] = __builtin_amdgcn_mfma_f32_16x16x32_bf16(al1, bh1, acc[1][1], 0, 0, 0);
    }

#pragma unroll
    for (int rt = 0; rt < 2; ++rt) {
#pragma unroll
        for (int ct = 0; ct < 2; ++ct) {
            floatx4 v = acc[rt][ct];
            int rbase = rt * 16 + quad * 4;
            int cp = (wcol0 + ct * 16) / 2 + (l15 >> 1);
#pragma unroll
            for (int r = 0; r < 4; ++r) {
                float mine = v[r] * normS[rbase + r];
                float oth = __shfl_xor(mine, 1, 64);
                uint32_t a = __float_as_uint((lane & 1) ? oth : mine);   // even col
                uint32_t b = __float_as_uint((lane & 1) ? mine : oth);   // odd col
                uint32_t packed = rne16(a) | (rne16(b) << 16);
                bool doit = ((lane & 1) == 0) ? (r < 2) : (r >= 2);
                if (doit)
                    ybf[(size_t)(row0 + rbase + r) * 64 + cp] = packed;
            }
        }
    }
}

// ---------------- SpMM: 1024 blocks x 512 thr = (bucket, quarter); 4 blocks/CU ----------------
__device__ __forceinline__ void fma8(float* acc, float v, uint4 u) {
    acc[0] = fmaf(v, __uint_as_float(u.x << 16), acc[0]);
    acc[1] = fmaf(v, __uint_as_float(u.x & 0xFFFF0000u), acc[1]);
    acc[2] = fmaf(v, __uint_as_float(u.y << 16), acc[2]);
    acc[3] = fmaf(v, __uint_as_float(u.y & 0xFFFF0000u), acc[3]);
    acc[4] = fmaf(v, __uint_as_float(u.z << 16), acc[4]);
    acc[5] = fmaf(v, __uint_as_float(u.z & 0xFFFF0000u), acc[5]);
    acc[6] = fmaf(v, __uint_as_float(u.w << 16), acc[6]);
    acc[7] = fmaf(v, __uint_as_float(u.w & 0xFFFF0000u), acc[7]);
}

__global__ __launch_bounds__(512, 8) void k_spmm(const uint32_t* __restrict__ gbkt,
                                                 const uint2* __restrict__ pack1,
                                                 const uint32_t* __restrict__ rowst,
                                                 const uint4* __restrict__ y4,
                                                 const float* __restrict__ norm,
                                                 const float* __restrict__ bias,
                                                 float* __restrict__ out) {
    __shared__ uint2    srt[CAPQ];     // 12 KB (node-sorted quarter-bucket)
    __shared__ uint32_t rs[65];        // local row starts + end sentinel
    __shared__ uint32_t rcur[64];
    int t = threadIdx.x;
    // blk -> (batch, bkt-in-batch, quarter) with XCD = blk%8 pinned to one batch's 4MB y-slab
    int blk = blockIdx.x;              // 0..1023
    int xcd = blk & 7;
    int batch = xcd & 3;
    int qhi = xcd >> 2;
    int j = blk >> 3;                  // 0..127
    int quarter = qhi * 2 + (j & 1);
    int bkt = batch * 64 + (j >> 1);
    int nbase = quarter * 64;
    uint32_t n = gbkt[bkt];
    if (t < 64) { rs[t] = rowst[bkt * NBKT + nbase + t]; rcur[t] = 0; }
    if (t == 64) rs[64] = (quarter == 3) ? n : rowst[bkt * NBKT + nbase + 64];
    __syncthreads();
    uint32_t qbase = rs[0];
    size_t base = (size_t)bkt * CAP;
    for (uint32_t i = t; i < n; i += 512) {
        uint2 p = pack1[base + i];
        uint32_t nl = p.x >> 14;
        if ((int)(nl >> 6) == quarter) {
            uint32_t loc = nl & 63;
            uint32_t pos = rs[loc] - qbase + atomicAdd(&rcur[loc], 1u);
            srt[pos] = p;
        }
    }
    __syncthreads();

    int wv = t >> 6;                   // 8 waves x 8 nodes each
    int lane = t & 63;
    int esub = lane >> 4;
    int chunk = lane & 15;
    uint32_t colbase = (uint32_t)batch << 14;   // batch*N_
#pragma unroll 1
    for (int i = 0; i < 8; ++i) {
        int nl = wv * 8 + i;           // 0..63 local
        uint32_t e = rs[nl] - qbase;
        uint32_t end = rs[nl + 1] - qbase;
        float acc[8] = {0.f,0.f,0.f,0.f,0.f,0.f,0.f,0.f};
        for (; e + 16 <= end; e += 16) {
            uint2 pa = srt[e + esub];
            uint2 pb = srt[e + 4 + esub];
            uint2 pc = srt[e + 8 + esub];
            uint2 pd = srt[e + 12 + esub];
            uint4 ua = y4[(size_t)(colbase | (pa.x & 0x3FFFu)) * 16 + chunk];
            uint4 ub = y4[(size_t)(colbase | (pb.x & 0x3FFFu)) * 16 + chunk];
            uint4 uc = y4[(size_t)(colbase | (pc.x & 0x3FFFu)) * 16 + chunk];
            uint4 ud = y4[(size_t)(colbase | (pd.x & 0x3FFFu)) * 16 + chunk];
            fma8(acc, __uint_as_float(pa.y), ua);
            fma8(acc, __uint_as_float(pb.y), ub);
            fma8(acc, __uint_as_float(pc.y), uc);
            fma8(acc, __uint_as_float(pd.y), ud);
        }
        for (; e + 4 <= end; e += 4) {
            uint2 p = srt[e + esub];
            uint4 u = y4[(size_t)(colbase | (p.x & 0x3FFFu)) * 16 + chunk];
            fma8(acc, __uint_as_float(p.y), u);
        }
        if (e < end) {
            uint32_t idx = e + esub;
            bool act = idx < end;
            uint2 p = srt[act ? idx : (end - 1)];
            uint4 u = y4[(size_t)(colbase | (p.x & 0x3FFFu)) * 16 + chunk];
            float v = act ? __uint_as_float(p.y) : 0.f;
            fma8(acc, v, u);
        }
#pragma unroll
        for (int jj = 0; jj < 8; ++jj) {
            acc[jj] += __shfl_xor(acc[jj], 16, 64);
            acc[jj] += __shfl_xor(acc[jj], 32, 64);
        }
        if (esub < 2) {
            int node = bkt * NBKT + nbase + nl;
            float nm = norm[node];
            float4 bb = ((const float4*)bias)[chunk * 2 + esub];
            float4 o;
            o.x = fmaxf(fmaf(acc[esub * 4 + 0], nm, bb.x), 0.f);
            o.y = fmaxf(fmaf(acc[esub * 4 + 1], nm, bb.y), 0.f);
            o.z = fmaxf(fmaf(acc[esub * 4 + 2], nm, bb.z), 0.f);
            o.w = fmaxf(fmaf(acc[esub * 4 + 3], nm, bb.w), 0.f);
            ((float4*)out)[(size_t)node * 32 + chunk * 2 + esub] = o;
        }
    }
}

extern "C" void kernel_launch(void* const* d_in, const int* in_sizes, int n_in,
                              void* d_out, int out_size, void* d_ws, size_t ws_size,
                              hipStream_t stream) {
    const float* x  = (const float*)d_in[0];
    const float* W  = (const float*)d_in[1];
    const float* bi = (const float*)d_in[2];
    const int* eb   = (const int*)d_in[3];
    const int* er   = (const int*)d_in[4];
    const int* ec   = (const int*)d_in[5];
    const float* ev = (const float*)d_in[6];
    float* out = (float*)d_out;

    char* ws = (char*)d_ws;
    uint32_t* ybf    = (uint32_t*)(ws + OFF_Y);
    uint2*    pack1  = (uint2*)(ws + OFF_PACK1);
    uint32_t* gbkt   = (uint32_t*)(ws + OFF_GBKT);
    float*    norm   = (float*)(ws + OFF_NORM);
    uint32_t* rowst  = (uint32_t*)(ws + OFF_ROWST);
    uint16_t* WhG    = (uint16_t*)(ws + OFF_WH);
    uint16_t* WlG    = (uint16_t*)(ws + OFF_WL);

    hipMemsetAsync(gbkt, 0, NBKT * sizeof(uint32_t), stream);
    k_scatter<<<NBLK, 1024, 0, stream>>>(eb, er, ec, ev, W, gbkt, pack1, WhG, WlG);
    k_degsort<<<NBKT, 1024, 0, stream>>>(gbkt, pack1, norm, rowst);
    k_matmul_mfma<<<BN_ / 32, 256, 0, stream>>>(x, WhG, WlG, norm, ybf);
    k_spmm   <<<1024, 512, 0, stream>>>(gbkt, pack1, rowst, (const uint4*)ybf, norm, bi, out);
}